// Round 5
// baseline (1652.859 us; speedup 1.0000x reference)
//
#include <hip/hip_runtime.h>
#include <cmath>

#define DEV __device__ __forceinline__

constexpr int NA    = 32768;          // atoms
constexpr int M     = 12;             // neighbors
constexpr int ORIG  = 92;
constexpr int NBR   = 41;
constexpr int AF    = 64;
constexpr int C2    = 128;            // 2*AF
constexpr int HF    = 128;
constexpr int NCONV = 3;
constexpr int NM    = NA * M;         // 393216
constexpr int BB    = 1024;           // crystals
constexpr int TA    = 4;              // atoms per tile
constexpr int RT    = TA * M;         // 48 rows per tile
constexpr int NTILES = NA / TA;       // 8192
constexpr int GRID_CONV = 2048;
constexpr int WLD   = 132;            // W2t row stride (2-way banks only = free)
constexpr int ALD   = 44;             // A tile row stride

DEV float fsig(float x) { return __builtin_amdgcn_rcpf(1.f + __expf(-x)); }
DEV float fsp (float x) { return fmaxf(x, 0.f) + __logf(1.f + __expf(-fabsf(x))); }

DEV void fma4(float4& a, float s, const float4 w) {
    a.x = fmaf(s, w.x, a.x); a.y = fmaf(s, w.y, a.y);
    a.z = fmaf(s, w.z, a.z); a.w = fmaf(s, w.w, a.w);
}
DEV float comp4(const float4 v, int i) { return i == 0 ? v.x : i == 1 ? v.y : i == 2 ? v.z : v.w; }
DEV void add4(float4& a, const float4 b) { a.x += b.x; a.y += b.y; a.z += b.z; a.w += b.w; }
DEV void sqa4(float4& a, const float4 b) {
    a.x = fmaf(b.x, b.x, a.x); a.y = fmaf(b.y, b.y, a.y);
    a.z = fmaf(b.z, b.z, a.z); a.w = fmaf(b.w, b.w, a.w);
}
DEV float4 shxor(const float4 v, int m) {
    float4 r;
    r.x = __shfl_xor(v.x, m, 64); r.y = __shfl_xor(v.y, m, 64);
    r.z = __shfl_xor(v.z, m, 64); r.w = __shfl_xor(v.w, m, 64);
    return r;
}
DEV void bfly4(float4& v) {              // 4-way sum across lanes xor 16,32
    float4 t = shxor(v, 16); add4(v, t);
    t = shxor(v, 32); add4(v, t);
}

// ---------------- embedding: x = atom_fea @ emb_W + emb_b ----------------
__global__ __launch_bounds__(256)
void embed_kernel(const float* __restrict__ atom_fea,
                  const float* __restrict__ Wm, const float* __restrict__ bm,
                  float* __restrict__ xo)
{
    __shared__ float af[4 * ORIG];
    const int a0 = blockIdx.x * 4, tid = threadIdx.x;
    for (int i = tid; i < 4 * ORIG; i += 256) af[i] = atom_fea[a0 * ORIG + i];
    __syncthreads();
    const int al = tid >> 6, c = tid & 63;
    float acc = bm[c];
    #pragma unroll 4
    for (int k = 0; k < ORIG; ++k) acc = fmaf(af[al * ORIG + k], Wm[k * AF + c], acc);
    xo[(a0 + al) * AF + c] = acc;
}

// ---------------- S = x@W[0:64] + b,  P = x@W[64:128]  (fused) ----------------
__global__ __launch_bounds__(256, 4)
void sp_kernel(const float* __restrict__ x,
               const float* __restrict__ W, const float* __restrict__ bias,
               float* __restrict__ S, float* __restrict__ P)
{
    __shared__ float xs[16][AF];
    const int a0 = blockIdx.x * 16, tid = threadIdx.x;
    {
        const int row = tid >> 4, c4 = (tid & 15) * 4;
        *(float4*)&xs[row][c4] = *(const float4*)(x + (size_t)(a0 + row) * AF + c4);
    }
    __syncthreads();
    const int cid = tid & 31, rid = tid >> 5;
    const int c0 = cid * 8, r0 = rid * 2;
    const bool isS = (c0 < 128);
    const int cc = c0 & 127;
    const float* Wb = W + (isS ? 0 : AF * C2) + cc;
    float* ob = (isS ? S : P);
    float4 a00, a01, a10, a11;
    if (isS) { a00 = *(const float4*)(bias + cc); a01 = *(const float4*)(bias + cc + 4); }
    else     { a00 = {0,0,0,0}; a01 = {0,0,0,0}; }
    a10 = a00; a11 = a01;
    for (int k = 0; k < AF; ++k) {
        const float4 w0 = *(const float4*)(Wb + k * C2);
        const float4 w1 = *(const float4*)(Wb + k * C2 + 4);
        const float x0 = xs[r0][k], x1 = xs[r0 + 1][k];
        fma4(a00, x0, w0); fma4(a01, x0, w1);
        fma4(a10, x1, w0); fma4(a11, x1, w1);
    }
    *(float4*)(ob + (size_t)(a0 + r0) * C2 + cc)     = a00;
    *(float4*)(ob + (size_t)(a0 + r0) * C2 + cc + 4) = a01;
    *(float4*)(ob + (size_t)(a0 + r0 + 1) * C2 + cc)     = a10;
    *(float4*)(ob + (size_t)(a0 + r0 + 1) * C2 + cc + 4) = a11;
}

// ------- conv core: g[n,m] = S[n] + P[idx[n,m]] + nbr[n,m]@W2 ------------------
// Software-pipelined one tile ahead (gathers + staging loads issued pre-GEMM).
// MODE 0: per-column sum/sumsq of g (BN1 stats partials).
// MODE 1: BN1-apply + sigmoid*softplus gate + sum over M -> summed; fused BN2
//         partial stats (sum/sumsq over atoms of summed).
template<int MODE>
__global__ __launch_bounds__(256, 4)
void conv5_kernel(const float* __restrict__ nbr_fea,
                  const int* __restrict__ idx,
                  const float* __restrict__ W2,
                  const float* __restrict__ S,
                  const float* __restrict__ P,
                  const float* __restrict__ ss1,    // [256] scale|shift (MODE1)
                  float* __restrict__ P1s, float* __restrict__ P1q,   // MODE0
                  float* __restrict__ summed,                          // MODE1
                  float* __restrict__ P2s, float* __restrict__ P2q)    // MODE1
{
    __shared__ float W2t[NBR * WLD];     // 21.6 KB
    __shared__ float sA[RT * ALD];       // 8.45 KB (tile; stats scratch at end)

    const int tid  = threadIdx.x;
    const int cid  = tid & 15;
    const int rid  = tid >> 4;
    const int cf   = cid * 4;            // filter col base; core col = cf + 64
    const int r0   = rid * 3;
    const int atom = tid >> 6;           // wave index == atom-in-tile

    for (int i = tid; i < NBR * 32; i += 256) {
        const int k = i >> 5, c4 = (i & 31) * 4;
        *(float4*)&W2t[k * WLD + c4] = *(const float4*)(W2 + k * C2 + c4);
    }

    // staging LDS offsets are tile-invariant: element e = tid + 256*i of the
    // contiguous 48x41 tile goes to sA[(e/41)*ALD + e%41]
    int soff[8];
    #pragma unroll
    for (int i = 0; i < 8; ++i) {
        const int e = tid + 256 * i;
        if (e < RT * NBR) {
            const int r = (int)(((unsigned)e * 102301u) >> 22);
            soff[i] = r * ALD + (e - r * NBR);
        } else soff[i] = -1;
    }

    float4 scf, scc, shf, shc;
    if (MODE == 1) {
        scf = *(const float4*)(ss1 + cf);        scc = *(const float4*)(ss1 + 64 + cf);
        shf = *(const float4*)(ss1 + C2 + cf);   shc = *(const float4*)(ss1 + C2 + 64 + cf);
    }

    const int stride = gridDim.x;
    int t = blockIdx.x;

    // ---- prologue: loads for first tile ----
    float nb[8];
    float4 pf0, pc0, pf1, pc1, pf2, pc2, svf, svc;
    {
        const int n0 = t * TA;
        const int j0 = idx[n0 * M + r0 + 0];
        const int j1 = idx[n0 * M + r0 + 1];
        const int j2 = idx[n0 * M + r0 + 2];
        const float* src = nbr_fea + (size_t)n0 * M * NBR;
        #pragma unroll
        for (int i = 0; i < 8; ++i) nb[i] = (soff[i] >= 0) ? src[tid + 256 * i] : 0.f;
        pf0 = *(const float4*)(P + (size_t)j0 * C2 + cf);
        pc0 = *(const float4*)(P + (size_t)j0 * C2 + 64 + cf);
        pf1 = *(const float4*)(P + (size_t)j1 * C2 + cf);
        pc1 = *(const float4*)(P + (size_t)j1 * C2 + 64 + cf);
        pf2 = *(const float4*)(P + (size_t)j2 * C2 + cf);
        pc2 = *(const float4*)(P + (size_t)j2 * C2 + 64 + cf);
        svf = *(const float4*)(S + (size_t)(n0 + atom) * C2 + cf);
        svc = *(const float4*)(S + (size_t)(n0 + atom) * C2 + 64 + cf);
    }

    float4 sum_f = {0,0,0,0}, sum_c = {0,0,0,0}, sq_f = {0,0,0,0}, sq_c = {0,0,0,0};
    float4 ts = {0,0,0,0}, tq = {0,0,0,0};   // MODE1 BN2 partials

    for (; t < NTILES; t += stride) {
        const int n0 = t * TA;
        const int tn = t + stride;

        __syncthreads();                 // prev tile LDS fully consumed
        #pragma unroll
        for (int i = 0; i < 8; ++i) if (soff[i] >= 0) sA[soff[i]] = nb[i];
        __syncthreads();

        // accumulators start at S + P[idx] (frees current gather regs now)
        float4 ef0 = svf, ec0 = svc, ef1 = svf, ec1 = svc, ef2 = svf, ec2 = svc;
        add4(ef0, pf0); add4(ec0, pc0);
        add4(ef1, pf1); add4(ec1, pc1);
        add4(ef2, pf2); add4(ec2, pc2);

        // ---- issue next tile's loads (latency hides behind the GEMM) ----
        if (tn < NTILES) {
            const int m0 = tn * TA;
            const float* srcn = nbr_fea + (size_t)m0 * M * NBR;
            #pragma unroll
            for (int i = 0; i < 8; ++i) nb[i] = (soff[i] >= 0) ? srcn[tid + 256 * i] : 0.f;
            const int j0 = idx[m0 * M + r0 + 0];
            const int j1 = idx[m0 * M + r0 + 1];
            const int j2 = idx[m0 * M + r0 + 2];
            pf0 = *(const float4*)(P + (size_t)j0 * C2 + cf);
            pc0 = *(const float4*)(P + (size_t)j0 * C2 + 64 + cf);
            pf1 = *(const float4*)(P + (size_t)j1 * C2 + cf);
            pc1 = *(const float4*)(P + (size_t)j1 * C2 + 64 + cf);
            pf2 = *(const float4*)(P + (size_t)j2 * C2 + cf);
            pc2 = *(const float4*)(P + (size_t)j2 * C2 + 64 + cf);
            svf = *(const float4*)(S + (size_t)(m0 + atom) * C2 + cf);
            svc = *(const float4*)(S + (size_t)(m0 + atom) * C2 + 64 + cf);
        }

        // ---- E-GEMM: += nbr @ W2 for 3 rows x (4+4) cols ----
        const float4* A0 = (const float4*)(sA + (r0 + 0) * ALD);
        const float4* A1 = (const float4*)(sA + (r0 + 1) * ALD);
        const float4* A2 = (const float4*)(sA + (r0 + 2) * ALD);
        #pragma unroll 2
        for (int k4 = 0; k4 < 10; ++k4) {
            const float4 a0 = A0[k4], a1 = A1[k4], a2 = A2[k4];
            #pragma unroll
            for (int kk = 0; kk < 4; ++kk) {
                const int k = 4 * k4 + kk;
                const float4 wf = *(const float4*)(W2t + k * WLD + cf);
                const float4 wc = *(const float4*)(W2t + k * WLD + 64 + cf);
                fma4(ef0, comp4(a0, kk), wf); fma4(ec0, comp4(a0, kk), wc);
                fma4(ef1, comp4(a1, kk), wf); fma4(ec1, comp4(a1, kk), wc);
                fma4(ef2, comp4(a2, kk), wf); fma4(ec2, comp4(a2, kk), wc);
            }
        }
        {   // k = 40
            const float4 wf = *(const float4*)(W2t + 40 * WLD + cf);
            const float4 wc = *(const float4*)(W2t + 40 * WLD + 64 + cf);
            const float a0s = sA[(r0 + 0) * ALD + 40];
            const float a1s = sA[(r0 + 1) * ALD + 40];
            const float a2s = sA[(r0 + 2) * ALD + 40];
            fma4(ef0, a0s, wf); fma4(ec0, a0s, wc);
            fma4(ef1, a1s, wf); fma4(ec1, a1s, wc);
            fma4(ef2, a2s, wf); fma4(ec2, a2s, wc);
        }

        if (MODE == 0) {
            add4(sum_f, ef0); add4(sum_f, ef1); add4(sum_f, ef2);
            add4(sum_c, ec0); add4(sum_c, ec1); add4(sum_c, ec2);
            sqa4(sq_f, ef0);  sqa4(sq_f, ef1);  sqa4(sq_f, ef2);
            sqa4(sq_c, ec0);  sqa4(sq_c, ec1);  sqa4(sq_c, ec2);
        } else {
            float4 part = {0,0,0,0};
            #pragma unroll
            for (int j = 0; j < 3; ++j) {
                const float4 gf = (j == 0) ? ef0 : (j == 1) ? ef1 : ef2;
                const float4 gc = (j == 0) ? ec0 : (j == 1) ? ec1 : ec2;
                float4 nf, nc;
                nf.x = fmaf(gf.x, scf.x, shf.x); nf.y = fmaf(gf.y, scf.y, shf.y);
                nf.z = fmaf(gf.z, scf.z, shf.z); nf.w = fmaf(gf.w, scf.w, shf.w);
                nc.x = fmaf(gc.x, scc.x, shc.x); nc.y = fmaf(gc.y, scc.y, shc.y);
                nc.z = fmaf(gc.z, scc.z, shc.z); nc.w = fmaf(gc.w, scc.w, shc.w);
                part.x = fmaf(fsig(nf.x), fsp(nc.x), part.x);
                part.y = fmaf(fsig(nf.y), fsp(nc.y), part.y);
                part.z = fmaf(fsig(nf.z), fsp(nc.z), part.z);
                part.w = fmaf(fsig(nf.w), fsp(nc.w), part.w);
            }
            bfly4(part);                 // all lanes now hold the M-sum for their cols
            if ((tid & 48) == 0) {
                *(float4*)(summed + (size_t)(n0 + atom) * AF + cf) = part;
                add4(ts, part);
                sqa4(tq, part);
            }
        }
    }

    if (MODE == 0) {   // block-level reduce of per-thread BN1 stats
        bfly4(sum_f); bfly4(sum_c); bfly4(sq_f); bfly4(sq_c);
        __syncthreads();                 // sA free (all tiles done)
        if ((tid & 48) == 0) {
            *(float4*)&sA[atom * C2 + cf]            = sum_f;
            *(float4*)&sA[atom * C2 + 64 + cf]       = sum_c;
            *(float4*)&sA[512 + atom * C2 + cf]      = sq_f;
            *(float4*)&sA[512 + atom * C2 + 64 + cf] = sq_c;
        }
        __syncthreads();
        if (tid < C2) {
            P1s[blockIdx.x * C2 + tid] = sA[tid] + sA[C2 + tid] + sA[2 * C2 + tid] + sA[3 * C2 + tid];
            P1q[blockIdx.x * C2 + tid] = sA[512 + tid] + sA[512 + C2 + tid]
                                       + sA[512 + 2 * C2 + tid] + sA[512 + 3 * C2 + tid];
        }
    } else {           // block-level reduce of BN2 partials (4 atom-groups x 64 cols)
        __syncthreads();                 // sA free
        if ((tid & 48) == 0) {
            *(float4*)&sA[atom * AF + cf]       = ts;
            *(float4*)&sA[256 + atom * AF + cf] = tq;
        }
        __syncthreads();
        if (tid < AF) {
            P2s[blockIdx.x * AF + tid] = sA[tid] + sA[AF + tid] + sA[2 * AF + tid] + sA[3 * AF + tid];
            P2q[blockIdx.x * AF + tid] = sA[256 + tid] + sA[256 + AF + tid]
                                       + sA[256 + 2 * AF + tid] + sA[256 + 3 * AF + tid];
        }
    }
}

// ---------------- BN stats finalize: partials -> per-column scale/shift ----------
__global__ __launch_bounds__(256)
void bn_finalize(const float* __restrict__ Ps, const float* __restrict__ Pq,
                 int npart, int C, float invn,
                 const float* __restrict__ gamma, const float* __restrict__ beta,
                 float* __restrict__ ss)
{
    __shared__ float sd[256];
    const int c = blockIdx.x, tid = threadIdx.x;
    float s = 0.f;
    for (int j = tid; j < npart; j += 256) s += Ps[j * C + c];
    sd[tid] = s; __syncthreads();
    for (int st = 128; st > 0; st >>= 1) { if (tid < st) sd[tid] += sd[tid + st]; __syncthreads(); }
    const float total = sd[0];
    __syncthreads();
    float q = 0.f;
    for (int j = tid; j < npart; j += 256) q += Pq[j * C + c];
    sd[tid] = q; __syncthreads();
    for (int st = 128; st > 0; st >>= 1) { if (tid < st) sd[tid] += sd[tid + st]; __syncthreads(); }
    if (tid == 0) {
        const float mean = total * invn;
        const float var  = sd[0] * invn - mean * mean;
        const float scl  = gamma[c] * rsqrtf(var + 1e-5f);
        ss[c]     = scl;
        ss[C + c] = beta[c] - mean * scl;
    }
}

// ---------------- x_out = softplus(x_in + bn2(summed)) ----------------
__global__ __launch_bounds__(256)
void update_x_kernel(const float* __restrict__ xin, const float* __restrict__ summed,
                     const float* __restrict__ ss2, float* __restrict__ xout)
{
    const int gid = blockIdx.x * 256 + threadIdx.x;
    const int base = gid * 4;
    const int c0 = base & 63;
    const float4 xi = *(const float4*)(xin + base);
    const float4 sm = *(const float4*)(summed + base);
    const float4 sc = *(const float4*)(ss2 + c0);
    const float4 sh = *(const float4*)(ss2 + AF + c0);
    float4 o;
    o.x = fsp(xi.x + fmaf(sm.x, sc.x, sh.x));
    o.y = fsp(xi.y + fmaf(sm.y, sc.y, sh.y));
    o.z = fsp(xi.z + fmaf(sm.z, sc.z, sh.z));
    o.w = fsp(xi.w + fmaf(sm.w, sc.w, sh.w));
    *(float4*)(xout + base) = o;
}

// ---------------- pool + MLP head ----------------
__global__ __launch_bounds__(128)
void head_kernel(const float* __restrict__ x,
                 const float* __restrict__ fc1W, const float* __restrict__ fc1b,
                 const float* __restrict__ fc2W, const float* __restrict__ fc2b,
                 const float* __restrict__ outW, const float* __restrict__ outb,
                 float* __restrict__ out)
{
    __shared__ float l0[AF], l1[HF], rr[2];
    const int b = blockIdx.x, tid = threadIdx.x;
    if (tid < AF) {
        float s = 0.f;
        #pragma unroll 4
        for (int a = 0; a < 32; ++a) s += x[(size_t)(b * 32 + a) * AF + tid];
        l0[tid] = fsp(s * (1.f / 32.f));
    }
    __syncthreads();
    float acc = fc1b[tid];
    #pragma unroll 4
    for (int k = 0; k < AF; ++k) acc = fmaf(l0[k], fc1W[k * HF + tid], acc);
    l1[tid] = fsp(acc);
    __syncthreads();
    acc = fc2b[tid];
    #pragma unroll 4
    for (int k = 0; k < HF; ++k) acc = fmaf(l1[k], fc2W[k * HF + tid], acc);
    float v = fsp(acc) * outW[tid];
    #pragma unroll
    for (int off = 32; off > 0; off >>= 1) v += __shfl_down(v, off, 64);
    if ((tid & 63) == 0) rr[tid >> 6] = v;
    __syncthreads();
    if (tid == 0) out[b] = rr[0] + rr[1] + outb[0];
}

extern "C" void kernel_launch(void* const* d_in, const int* in_sizes, int n_in,
                              void* d_out, int out_size, void* d_ws, size_t ws_size,
                              hipStream_t stream)
{
    const float* atom_fea = (const float*)d_in[0];
    const float* nbr_fea  = (const float*)d_in[1];
    const int*   nbr_idx  = (const int*)d_in[2];
    const float* emb_W  = (const float*)d_in[4];
    const float* emb_b  = (const float*)d_in[5];
    const float* conv_W = (const float*)d_in[6];
    const float* conv_b = (const float*)d_in[7];
    const float* bn1_g  = (const float*)d_in[8];
    const float* bn1_b  = (const float*)d_in[9];
    const float* bn2_g  = (const float*)d_in[10];
    const float* bn2_b  = (const float*)d_in[11];
    const float* fc1W   = (const float*)d_in[12];
    const float* fc1b   = (const float*)d_in[13];
    const float* fc2W   = (const float*)d_in[14];
    const float* fc2b   = (const float*)d_in[15];
    const float* outW   = (const float*)d_in[16];
    const float* outb   = (const float*)d_in[17];
    float* out = (float*)d_out;
    float* ws  = (float*)d_ws;

    float* x_a    = ws;
    float* x_b    = x_a + (size_t)NA * AF;
    float* Sbuf   = x_b + (size_t)NA * AF;
    float* Pbuf   = Sbuf + (size_t)NA * C2;
    float* summed = Pbuf + (size_t)NA * C2;
    float* P1s    = summed + (size_t)NA * AF;
    float* P1q    = P1s + GRID_CONV * C2;
    float* P2s    = P1q + GRID_CONV * C2;
    float* P2q    = P2s + GRID_CONV * AF;
    float* ss1    = P2q + GRID_CONV * AF;
    float* ss2    = ss1 + 2 * C2;

    embed_kernel<<<NA / 4, 256, 0, stream>>>(atom_fea, emb_W, emb_b, x_a);

    float* xin = x_a; float* xout = x_b;
    for (int l = 0; l < NCONV; ++l) {
        const float* Wl = conv_W + (size_t)l * (2 * AF + NBR) * C2;
        const float* bl = conv_b + (size_t)l * C2;
        const float* W2 = Wl + C2 * C2;

        sp_kernel<<<NA / 16, 256, 0, stream>>>(xin, Wl, bl, Sbuf, Pbuf);
        conv5_kernel<0><<<GRID_CONV, 256, 0, stream>>>(nbr_fea, nbr_idx, W2, Sbuf, Pbuf,
                                                       nullptr, P1s, P1q,
                                                       nullptr, nullptr, nullptr);
        bn_finalize<<<C2, 256, 0, stream>>>(P1s, P1q, GRID_CONV, C2, 1.f / (float)NM,
                                            bn1_g + l * C2, bn1_b + l * C2, ss1);
        conv5_kernel<1><<<GRID_CONV, 256, 0, stream>>>(nbr_fea, nbr_idx, W2, Sbuf, Pbuf,
                                                       ss1, nullptr, nullptr,
                                                       summed, P2s, P2q);
        bn_finalize<<<AF, 256, 0, stream>>>(P2s, P2q, GRID_CONV, AF, 1.f / (float)NA,
                                            bn2_g + l * AF, bn2_b + l * AF, ss2);
        update_x_kernel<<<NA * AF / 4 / 256, 256, 0, stream>>>(xin, summed, ss2, xout);
        float* tmp = xin; xin = xout; xout = tmp;
    }
    head_kernel<<<BB, 128, 0, stream>>>(xin, fc1W, fc1b, fc2W, fc2b, outW, outb, out);
}

// Round 6
// 1152.941 us; speedup vs baseline: 1.4336x; 1.4336x over previous
//
#include <hip/hip_runtime.h>
#include <cmath>

#define DEV __device__ __forceinline__

constexpr int NA    = 32768;          // atoms
constexpr int M     = 12;             // neighbors
constexpr int ORIG  = 92;
constexpr int NBR   = 41;
constexpr int AF    = 64;
constexpr int C2    = 128;            // 2*AF
constexpr int HF    = 128;
constexpr int NCONV = 3;
constexpr int NM    = NA * M;         // 393216
constexpr int BB    = 1024;           // crystals
constexpr int TA    = 4;              // atoms per tile
constexpr int RT    = TA * M;         // 48 rows per tile
constexpr int NTILES = NA / TA;       // 8192
constexpr int GRID_CONV = 2048;
constexpr int WLD   = 132;            // W2t row stride (2-way banks only = free)
constexpr int ALD   = 44;             // A tile row stride (16B-aligned rows)

DEV float fsig(float x) { return __builtin_amdgcn_rcpf(1.f + __expf(-x)); }
DEV float fsp (float x) { return fmaxf(x, 0.f) + __logf(1.f + __expf(-fabsf(x))); }

DEV void fma4(float4& a, float s, const float4 w) {
    a.x = fmaf(s, w.x, a.x); a.y = fmaf(s, w.y, a.y);
    a.z = fmaf(s, w.z, a.z); a.w = fmaf(s, w.w, a.w);
}
DEV float comp4(const float4 v, int i) { return i == 0 ? v.x : i == 1 ? v.y : i == 2 ? v.z : v.w; }
DEV void add4(float4& a, const float4 b) { a.x += b.x; a.y += b.y; a.z += b.z; a.w += b.w; }
DEV void sqa4(float4& a, const float4 b) {
    a.x = fmaf(b.x, b.x, a.x); a.y = fmaf(b.y, b.y, a.y);
    a.z = fmaf(b.z, b.z, a.z); a.w = fmaf(b.w, b.w, a.w);
}
DEV float4 shxor(const float4 v, int m) {
    float4 r;
    r.x = __shfl_xor(v.x, m, 64); r.y = __shfl_xor(v.y, m, 64);
    r.z = __shfl_xor(v.z, m, 64); r.w = __shfl_xor(v.w, m, 64);
    return r;
}
DEV void bfly4(float4& v) {              // 4-way sum across lanes xor 16,32
    float4 t = shxor(v, 16); add4(v, t);
    t = shxor(v, 32); add4(v, t);
}
DEV unsigned bf16pair(float a, float b) {   // RNE pack: low=a, high=b
    unsigned ua = __float_as_uint(a), ub = __float_as_uint(b);
    ua += 0x7fffu + ((ua >> 16) & 1u);
    ub += 0x7fffu + ((ub >> 16) & 1u);
    return (ua >> 16) | (ub & 0xffff0000u);
}
DEV float4 up4(const uint2 q) {             // unpack 4 bf16 -> float4
    float4 r;
    r.x = __uint_as_float(q.x << 16);
    r.y = __uint_as_float(q.x & 0xffff0000u);
    r.z = __uint_as_float(q.y << 16);
    r.w = __uint_as_float(q.y & 0xffff0000u);
    return r;
}

// ---- spx: x-update (embed for layer0, softplus(x+bn2(summed)) otherwise)
//      fused with S = x@W[0:64]+b (fp32) and P = x@W[64:128] (packed bf16) ----
template<bool FIRST>
__global__ __launch_bounds__(256, 4)
void spx_kernel(const float* __restrict__ xin,
                const float* __restrict__ summed,
                const float* __restrict__ ss2,
                const float* __restrict__ atom_fea,
                const float* __restrict__ embW,
                const float* __restrict__ embb,
                const float* __restrict__ W,      // layer's conv_W (rows 0..127 used)
                const float* __restrict__ bias,   // layer's conv_b
                float* __restrict__ xout,
                float* __restrict__ S,
                unsigned* __restrict__ Pb)
{
    __shared__ float xs[16][AF];
    __shared__ float af[FIRST ? 16 * ORIG : 4];

    const int a0 = blockIdx.x * 16, tid = threadIdx.x;

    if (FIRST) {
        for (int i = tid; i < 16 * ORIG; i += 256) af[i] = atom_fea[(size_t)a0 * ORIG + i];
        __syncthreads();
        const int row = tid >> 4, c4 = (tid & 15) * 4;
        float4 acc = *(const float4*)(embb + c4);
        #pragma unroll 4
        for (int k = 0; k < ORIG; ++k)
            fma4(acc, af[row * ORIG + k], *(const float4*)(embW + k * AF + c4));
        *(float4*)&xs[row][c4] = acc;
        *(float4*)(xout + (size_t)(a0 + row) * AF + c4) = acc;
    } else {
        const int row = tid >> 4, c4 = (tid & 15) * 4;
        const size_t o = (size_t)(a0 + row) * AF + c4;
        const float4 xi = *(const float4*)(xin + o);
        const float4 sm = *(const float4*)(summed + o);
        const float4 sc = *(const float4*)(ss2 + c4);
        const float4 sh = *(const float4*)(ss2 + AF + c4);
        float4 ov;
        ov.x = fsp(xi.x + fmaf(sm.x, sc.x, sh.x));
        ov.y = fsp(xi.y + fmaf(sm.y, sc.y, sh.y));
        ov.z = fsp(xi.z + fmaf(sm.z, sc.z, sh.z));
        ov.w = fsp(xi.w + fmaf(sm.w, sc.w, sh.w));
        *(float4*)&xs[row][c4] = ov;
        *(float4*)(xout + o) = ov;
    }
    __syncthreads();

    // S/P GEMM: 32 col-threads (8 cols) x 8 row-threads (2 rows)
    const int cid = tid & 31, rid = tid >> 5;
    const int c0 = cid * 8, r0 = rid * 2;
    const bool isS = (c0 < 128);
    const int cc = c0 & 127;
    const float* Wb = W + (isS ? 0 : AF * C2) + cc;
    float4 a00, a01, a10, a11;
    if (isS) { a00 = *(const float4*)(bias + cc); a01 = *(const float4*)(bias + cc + 4); }
    else     { a00 = {0,0,0,0}; a01 = {0,0,0,0}; }
    a10 = a00; a11 = a01;
    for (int k = 0; k < AF; ++k) {
        const float4 w0 = *(const float4*)(Wb + k * C2);
        const float4 w1 = *(const float4*)(Wb + k * C2 + 4);
        const float x0 = xs[r0][k], x1 = xs[r0 + 1][k];
        fma4(a00, x0, w0); fma4(a01, x0, w1);
        fma4(a10, x1, w0); fma4(a11, x1, w1);
    }
    if (isS) {
        *(float4*)(S + (size_t)(a0 + r0) * C2 + cc)     = a00;
        *(float4*)(S + (size_t)(a0 + r0) * C2 + cc + 4) = a01;
        *(float4*)(S + (size_t)(a0 + r0 + 1) * C2 + cc)     = a10;
        *(float4*)(S + (size_t)(a0 + r0 + 1) * C2 + cc + 4) = a11;
    } else {
        uint4 u0, u1;
        u0.x = bf16pair(a00.x, a00.y); u0.y = bf16pair(a00.z, a00.w);
        u0.z = bf16pair(a01.x, a01.y); u0.w = bf16pair(a01.z, a01.w);
        u1.x = bf16pair(a10.x, a10.y); u1.y = bf16pair(a10.z, a10.w);
        u1.z = bf16pair(a11.x, a11.y); u1.w = bf16pair(a11.z, a11.w);
        *(uint4*)(Pb + (size_t)(a0 + r0) * 64 + cc / 2)     = u0;
        *(uint4*)(Pb + (size_t)(a0 + r0 + 1) * 64 + cc / 2) = u1;
    }
}

// ------- conv core: g[n,m] = S[n] + P[idx[n,m]] + nbr[n,m]@W2 ------------------
// Register-frugal pipeline: only idx prefetched cross-iteration (3 regs); P/S
// issued at GEMM start, consumed in the epilogue (acc runs from 0); nbr staging
// loads issued pre-GEMM, LDS-written next iteration (8 regs).
// MODE 0: per-column sum/sumsq of g (BN1 stats partials).
// MODE 1: BN1-apply + gate + sum over M -> summed; fused BN2 partial stats.
template<int MODE>
__global__ __launch_bounds__(256, 4)
void conv6_kernel(const float* __restrict__ nbr_fea,
                  const int* __restrict__ idx,
                  const float* __restrict__ W2,
                  const float* __restrict__ S,
                  const unsigned* __restrict__ Pb,
                  const float* __restrict__ ss1,
                  float* __restrict__ P1s, float* __restrict__ P1q,
                  float* __restrict__ summed,
                  float* __restrict__ P2s, float* __restrict__ P2q)
{
    __shared__ float W2t[NBR * WLD];     // 21.6 KB
    __shared__ float sA[RT * ALD];       // 8.45 KB

    const int tid  = threadIdx.x;
    const int cid  = tid & 15;
    const int rid  = tid >> 4;
    const int cf   = cid * 4;            // filter col base; core col = cf + 64
    const int r0   = rid * 3;
    const int atom = tid >> 6;           // wave index == atom-in-tile

    for (int i = tid; i < NBR * 32; i += 256) {
        const int k = i >> 5, c4 = (i & 31) * 4;
        *(float4*)&W2t[k * WLD + c4] = *(const float4*)(W2 + k * C2 + c4);
    }

    // staging LDS offsets tile-invariant: element e -> sA[(e/41)*ALD + e%41]
    int soff[8];
    #pragma unroll
    for (int i = 0; i < 8; ++i) {
        const int e = tid + 256 * i;
        if (e < RT * NBR) {
            const int r = (int)(((unsigned)e * 102301u) >> 22);
            soff[i] = r * ALD + (e - r * NBR);
        } else soff[i] = -1;
    }

    float4 scf, scc, shf, shc;
    if (MODE == 1) {
        scf = *(const float4*)(ss1 + cf);        scc = *(const float4*)(ss1 + 64 + cf);
        shf = *(const float4*)(ss1 + C2 + cf);   shc = *(const float4*)(ss1 + C2 + 64 + cf);
    }

    const int stride = gridDim.x;
    int t = blockIdx.x;

    // prologue: first tile's idx + nbr loads
    float nb[8];
    int jn0, jn1, jn2;
    {
        const int n0 = t * TA;
        jn0 = idx[n0 * M + r0 + 0];
        jn1 = idx[n0 * M + r0 + 1];
        jn2 = idx[n0 * M + r0 + 2];
        const float* src = nbr_fea + (size_t)n0 * M * NBR;
        #pragma unroll
        for (int i = 0; i < 8; ++i) nb[i] = (soff[i] >= 0) ? src[tid + 256 * i] : 0.f;
    }

    float4 sum_f = {0,0,0,0}, sum_c = {0,0,0,0}, sq_f = {0,0,0,0}, sq_c = {0,0,0,0};
    float4 ts = {0,0,0,0}, tq = {0,0,0,0};   // MODE1 BN2 partials

    for (; t < NTILES; t += stride) {
        const int n0 = t * TA;
        const int tc = (t + stride < NTILES) ? (t + stride) : t;   // clamped next

        __syncthreads();                 // prev tile LDS fully consumed
        #pragma unroll
        for (int i = 0; i < 8; ++i) if (soff[i] >= 0) sA[soff[i]] = nb[i];
        __syncthreads();

        // far loads for CURRENT tile -- consumed after the GEMM (epilogue)
        const float4 svf = *(const float4*)(S + (size_t)(n0 + atom) * C2 + cf);
        const float4 svc = *(const float4*)(S + (size_t)(n0 + atom) * C2 + 64 + cf);
        const uint2 q0f = *(const uint2*)(Pb + (size_t)jn0 * 64 + 2 * cid);
        const uint2 q0c = *(const uint2*)(Pb + (size_t)jn0 * 64 + 32 + 2 * cid);
        const uint2 q1f = *(const uint2*)(Pb + (size_t)jn1 * 64 + 2 * cid);
        const uint2 q1c = *(const uint2*)(Pb + (size_t)jn1 * 64 + 32 + 2 * cid);
        const uint2 q2f = *(const uint2*)(Pb + (size_t)jn2 * 64 + 2 * cid);
        const uint2 q2c = *(const uint2*)(Pb + (size_t)jn2 * 64 + 32 + 2 * cid);

        // prefetch NEXT tile: idx (for next iter's gathers) + nbr staging regs
        {
            const int m0 = tc * TA;
            jn0 = idx[m0 * M + r0 + 0];
            jn1 = idx[m0 * M + r0 + 1];
            jn2 = idx[m0 * M + r0 + 2];
            const float* srcn = nbr_fea + (size_t)m0 * M * NBR;
            #pragma unroll
            for (int i = 0; i < 8; ++i) nb[i] = (soff[i] >= 0) ? srcn[tid + 256 * i] : 0.f;
        }

        // ---- E-GEMM from zero: nbr @ W2, 3 rows x (4+4) cols ----
        float4 ef0={0,0,0,0}, ec0={0,0,0,0}, ef1={0,0,0,0}, ec1={0,0,0,0}, ef2={0,0,0,0}, ec2={0,0,0,0};
        const float4* A0 = (const float4*)(sA + (r0 + 0) * ALD);
        const float4* A1 = (const float4*)(sA + (r0 + 1) * ALD);
        const float4* A2 = (const float4*)(sA + (r0 + 2) * ALD);
        #pragma unroll 2
        for (int k4 = 0; k4 < 10; ++k4) {
            const float4 a0 = A0[k4], a1 = A1[k4], a2 = A2[k4];
            #pragma unroll
            for (int kk = 0; kk < 4; ++kk) {
                const int k = 4 * k4 + kk;
                const float4 wf = *(const float4*)(W2t + k * WLD + cf);
                const float4 wc = *(const float4*)(W2t + k * WLD + 64 + cf);
                fma4(ef0, comp4(a0, kk), wf); fma4(ec0, comp4(a0, kk), wc);
                fma4(ef1, comp4(a1, kk), wf); fma4(ec1, comp4(a1, kk), wc);
                fma4(ef2, comp4(a2, kk), wf); fma4(ec2, comp4(a2, kk), wc);
            }
        }
        {   // k = 40
            const float4 wf = *(const float4*)(W2t + 40 * WLD + cf);
            const float4 wc = *(const float4*)(W2t + 40 * WLD + 64 + cf);
            const float a0s = sA[(r0 + 0) * ALD + 40];
            const float a1s = sA[(r0 + 1) * ALD + 40];
            const float a2s = sA[(r0 + 2) * ALD + 40];
            fma4(ef0, a0s, wf); fma4(ec0, a0s, wc);
            fma4(ef1, a1s, wf); fma4(ec1, a1s, wc);
            fma4(ef2, a2s, wf); fma4(ec2, a2s, wc);
        }

        // ---- epilogue: g = E + S + P[idx] (gathers have had the GEMM to land) ----
        add4(ef0, svf); add4(ef0, up4(q0f));  add4(ec0, svc); add4(ec0, up4(q0c));
        add4(ef1, svf); add4(ef1, up4(q1f));  add4(ec1, svc); add4(ec1, up4(q1c));
        add4(ef2, svf); add4(ef2, up4(q2f));  add4(ec2, svc); add4(ec2, up4(q2c));

        if (MODE == 0) {
            add4(sum_f, ef0); add4(sum_f, ef1); add4(sum_f, ef2);
            add4(sum_c, ec0); add4(sum_c, ec1); add4(sum_c, ec2);
            sqa4(sq_f, ef0);  sqa4(sq_f, ef1);  sqa4(sq_f, ef2);
            sqa4(sq_c, ec0);  sqa4(sq_c, ec1);  sqa4(sq_c, ec2);
        } else {
            float4 part = {0,0,0,0};
            #pragma unroll
            for (int j = 0; j < 3; ++j) {
                const float4 gf = (j == 0) ? ef0 : (j == 1) ? ef1 : ef2;
                const float4 gc = (j == 0) ? ec0 : (j == 1) ? ec1 : ec2;
                float4 nf, nc;
                nf.x = fmaf(gf.x, scf.x, shf.x); nf.y = fmaf(gf.y, scf.y, shf.y);
                nf.z = fmaf(gf.z, scf.z, shf.z); nf.w = fmaf(gf.w, scf.w, shf.w);
                nc.x = fmaf(gc.x, scc.x, shc.x); nc.y = fmaf(gc.y, scc.y, shc.y);
                nc.z = fmaf(gc.z, scc.z, shc.z); nc.w = fmaf(gc.w, scc.w, shc.w);
                part.x = fmaf(fsig(nf.x), fsp(nc.x), part.x);
                part.y = fmaf(fsig(nf.y), fsp(nc.y), part.y);
                part.z = fmaf(fsig(nf.z), fsp(nc.z), part.z);
                part.w = fmaf(fsig(nf.w), fsp(nc.w), part.w);
            }
            bfly4(part);
            if ((tid & 48) == 0) {
                *(float4*)(summed + (size_t)(n0 + atom) * AF + cf) = part;
                add4(ts, part);
                sqa4(tq, part);
            }
        }
    }

    if (MODE == 0) {   // block-level reduce of per-thread BN1 stats
        bfly4(sum_f); bfly4(sum_c); bfly4(sq_f); bfly4(sq_c);
        __syncthreads();                 // sA free (all tiles done)
        if ((tid & 48) == 0) {
            *(float4*)&sA[atom * C2 + cf]            = sum_f;
            *(float4*)&sA[atom * C2 + 64 + cf]       = sum_c;
            *(float4*)&sA[512 + atom * C2 + cf]      = sq_f;
            *(float4*)&sA[512 + atom * C2 + 64 + cf] = sq_c;
        }
        __syncthreads();
        if (tid < C2) {
            P1s[blockIdx.x * C2 + tid] = sA[tid] + sA[C2 + tid] + sA[2 * C2 + tid] + sA[3 * C2 + tid];
            P1q[blockIdx.x * C2 + tid] = sA[512 + tid] + sA[512 + C2 + tid]
                                       + sA[512 + 2 * C2 + tid] + sA[512 + 3 * C2 + tid];
        }
    } else {           // block-level reduce of BN2 partials
        __syncthreads();
        if ((tid & 48) == 0) {
            *(float4*)&sA[atom * AF + cf]       = ts;
            *(float4*)&sA[256 + atom * AF + cf] = tq;
        }
        __syncthreads();
        if (tid < AF) {
            P2s[blockIdx.x * AF + tid] = sA[tid] + sA[AF + tid] + sA[2 * AF + tid] + sA[3 * AF + tid];
            P2q[blockIdx.x * AF + tid] = sA[256 + tid] + sA[256 + AF + tid]
                                       + sA[256 + 2 * AF + tid] + sA[256 + 3 * AF + tid];
        }
    }
}

// ---------------- BN stats finalize: partials -> per-column scale/shift ----------
__global__ __launch_bounds__(256)
void bn_finalize(const float* __restrict__ Ps, const float* __restrict__ Pq,
                 int npart, int C, float invn,
                 const float* __restrict__ gamma, const float* __restrict__ beta,
                 float* __restrict__ ss)
{
    __shared__ float sd[256];
    const int c = blockIdx.x, tid = threadIdx.x;
    float s = 0.f;
    for (int j = tid; j < npart; j += 256) s += Ps[j * C + c];
    sd[tid] = s; __syncthreads();
    for (int st = 128; st > 0; st >>= 1) { if (tid < st) sd[tid] += sd[tid + st]; __syncthreads(); }
    const float total = sd[0];
    __syncthreads();
    float q = 0.f;
    for (int j = tid; j < npart; j += 256) q += Pq[j * C + c];
    sd[tid] = q; __syncthreads();
    for (int st = 128; st > 0; st >>= 1) { if (tid < st) sd[tid] += sd[tid + st]; __syncthreads(); }
    if (tid == 0) {
        const float mean = total * invn;
        const float var  = sd[0] * invn - mean * mean;
        const float scl  = gamma[c] * rsqrtf(var + 1e-5f);
        ss[c]     = scl;
        ss[C + c] = beta[c] - mean * scl;
    }
}

// ---------------- head: fused x-update + pool + MLP ----------------
__global__ __launch_bounds__(128)
void head_kernel(const float* __restrict__ x,
                 const float* __restrict__ summed,
                 const float* __restrict__ ss2,
                 const float* __restrict__ fc1W, const float* __restrict__ fc1b,
                 const float* __restrict__ fc2W, const float* __restrict__ fc2b,
                 const float* __restrict__ outW, const float* __restrict__ outb,
                 float* __restrict__ out)
{
    __shared__ float l0[AF], l1[HF], rr[2], hs[2][AF];
    const int b = blockIdx.x, tid = threadIdx.x;
    const int col = tid & 63, half = tid >> 6;
    {
        const float sc = ss2[col], sh = ss2[AF + col];
        float s = 0.f;
        #pragma unroll 4
        for (int a = half * 16; a < half * 16 + 16; ++a) {
            const size_t o = (size_t)(b * 32 + a) * AF + col;
            s += fsp(x[o] + fmaf(summed[o], sc, sh));
        }
        hs[half][col] = s;
    }
    __syncthreads();
    if (tid < AF) l0[tid] = fsp((hs[0][tid] + hs[1][tid]) * (1.f / 32.f));
    __syncthreads();
    float acc = fc1b[tid];
    #pragma unroll 4
    for (int k = 0; k < AF; ++k) acc = fmaf(l0[k], fc1W[k * HF + tid], acc);
    l1[tid] = fsp(acc);
    __syncthreads();
    acc = fc2b[tid];
    #pragma unroll 4
    for (int k = 0; k < HF; ++k) acc = fmaf(l1[k], fc2W[k * HF + tid], acc);
    float v = fsp(acc) * outW[tid];
    #pragma unroll
    for (int off = 32; off > 0; off >>= 1) v += __shfl_down(v, off, 64);
    if ((tid & 63) == 0) rr[tid >> 6] = v;
    __syncthreads();
    if (tid == 0) out[b] = rr[0] + rr[1] + outb[0];
}

extern "C" void kernel_launch(void* const* d_in, const int* in_sizes, int n_in,
                              void* d_out, int out_size, void* d_ws, size_t ws_size,
                              hipStream_t stream)
{
    const float* atom_fea = (const float*)d_in[0];
    const float* nbr_fea  = (const float*)d_in[1];
    const int*   nbr_idx  = (const int*)d_in[2];
    const float* emb_W  = (const float*)d_in[4];
    const float* emb_b  = (const float*)d_in[5];
    const float* conv_W = (const float*)d_in[6];
    const float* conv_b = (const float*)d_in[7];
    const float* bn1_g  = (const float*)d_in[8];
    const float* bn1_b  = (const float*)d_in[9];
    const float* bn2_g  = (const float*)d_in[10];
    const float* bn2_b  = (const float*)d_in[11];
    const float* fc1W   = (const float*)d_in[12];
    const float* fc1b   = (const float*)d_in[13];
    const float* fc2W   = (const float*)d_in[14];
    const float* fc2b   = (const float*)d_in[15];
    const float* outW   = (const float*)d_in[16];
    const float* outb   = (const float*)d_in[17];
    float* out = (float*)d_out;
    float* ws  = (float*)d_ws;

    float*    x_a    = ws;
    float*    x_b    = x_a + (size_t)NA * AF;
    float*    Sbuf   = x_b + (size_t)NA * AF;
    unsigned* Pb     = (unsigned*)(Sbuf + (size_t)NA * C2);   // NA x 64 uints (bf16 pairs)
    float*    summed = (float*)(Pb + (size_t)NA * 64);
    float*    P1s    = summed + (size_t)NA * AF;
    float*    P1q    = P1s + GRID_CONV * C2;
    float*    P2s    = P1q + GRID_CONV * C2;
    float*    P2q    = P2s + GRID_CONV * AF;
    float*    ss1    = P2q + GRID_CONV * AF;
    float*    ss2    = ss1 + 2 * C2;

    float* xcur = x_a;
    // layer 0 spx: embed + S/P
    spx_kernel<true><<<NA / 16, 256, 0, stream>>>(nullptr, nullptr, nullptr,
                                                  atom_fea, emb_W, emb_b,
                                                  conv_W, conv_b, xcur, Sbuf, Pb);
    for (int l = 0; l < NCONV; ++l) {
        conv6_kernel<0><<<GRID_CONV, 256, 0, stream>>>(nbr_fea, nbr_idx,
                                                       conv_W + (size_t)l * (C2 + NBR) * C2 + (size_t)C2 * C2,
                                                       Sbuf, Pb, nullptr, P1s, P1q,
                                                       nullptr, nullptr, nullptr);
        bn_finalize<<<C2, 256, 0, stream>>>(P1s, P1q, GRID_CONV, C2, 1.f / (float)NM,
                                            bn1_g + l * C2, bn1_b + l * C2, ss1);
        conv6_kernel<1><<<GRID_CONV, 256, 0, stream>>>(nbr_fea, nbr_idx,
                                                       conv_W + (size_t)l * (C2 + NBR) * C2 + (size_t)C2 * C2,
                                                       Sbuf, Pb, ss1, nullptr, nullptr,
                                                       summed, P2s, P2q);
        bn_finalize<<<AF, 256, 0, stream>>>(P2s, P2q, GRID_CONV, AF, 1.f / (float)NA,
                                            bn2_g + l * AF, bn2_b + l * AF, ss2);
        if (l < NCONV - 1) {
            float* xnext = (xcur == x_a) ? x_b : x_a;
            spx_kernel<false><<<NA / 16, 256, 0, stream>>>(xcur, summed, ss2,
                                                           nullptr, nullptr, nullptr,
                                                           conv_W + (size_t)(l + 1) * (C2 + NBR) * C2,
                                                           conv_b + (size_t)(l + 1) * C2,
                                                           xnext, Sbuf, Pb);
            xcur = xnext;
        }
    }
    head_kernel<<<BB, 128, 0, stream>>>(xcur, summed, ss2,
                                        fc1W, fc1b, fc2W, fc2b, outW, outb, out);
}